// Round 3
// baseline (1732.602 us; speedup 1.0000x reference)
//
#include <hip/hip_runtime.h>

#define BB 4
#define TT 2048
#define SSZ 2048
#define DQq 512
#define NH 8
#define HDim 64

typedef __attribute__((ext_vector_type(4))) float f32x4;

// ---------------- projection GEMM f32: Out = X[M,Kd] @ W[Kd,512] + bias
// W consumed in natural [k][n] layout (no transpose).
// MODE 0: scatter to [B,H,L,64] (L = 2048 = TT = SSZ); MODE 1: flat [M,512]
template<int MODE>
__global__ __launch_bounds__(256) void proj_f32(
    const float* __restrict__ X, const float* __restrict__ W,
    const float* __restrict__ bias, float* __restrict__ Out, int Kd)
{
    __shared__ float As[64][17];
    __shared__ float Bs[16][65];
    int tid = threadIdx.x;
    int m0 = blockIdx.x * 64, n0 = blockIdx.y * 64;
    int ty = tid >> 4, tx = tid & 15;   // ty,tx in [0,16)

    float acc[4][4];
    for (int i = 0; i < 4; ++i)
        for (int j = 0; j < 4; ++j) acc[i][j] = 0.f;

    for (int k0 = 0; k0 < Kd; k0 += 16) {
        for (int p = 0; p < 4; ++p) {
            int x = tid + p * 256;                     // 1024 elements each
            As[x >> 4][x & 15] = X[(size_t)(m0 + (x >> 4)) * Kd + k0 + (x & 15)];
            Bs[x >> 6][x & 63] = W[(size_t)(k0 + (x >> 6)) * DQq + n0 + (x & 63)];
        }
        __syncthreads();
        for (int kk = 0; kk < 16; ++kk) {
            float a[4], b[4];
            for (int i = 0; i < 4; ++i) a[i] = As[ty * 4 + i][kk];
            for (int j = 0; j < 4; ++j) b[j] = Bs[kk][tx * 4 + j];
            for (int i = 0; i < 4; ++i)
                for (int j = 0; j < 4; ++j) acc[i][j] += a[i] * b[j];
        }
        __syncthreads();
    }

    for (int i = 0; i < 4; ++i)
        for (int j = 0; j < 4; ++j) {
            int m = m0 + ty * 4 + i, n = n0 + tx * 4 + j;
            float v = acc[i][j] + bias[n];
            if (MODE == 0) {
                int b = m >> 11, t = m & 2047, h = n >> 6, hd = n & 63;
                Out[((((size_t)b * NH + h) * TT + t) << 6) + hd] = v;
            } else {
                Out[(size_t)m * DQq + n] = v;
            }
        }
}

// ---------------- raw scores: Sc[bh][t][s] = Q.K/8 + amask, masked -> -1e30
__global__ __launch_bounds__(256) void scores_f32(
    const float* __restrict__ Q, const float* __restrict__ K,
    const int* __restrict__ kpm, const float* __restrict__ amask,
    float* __restrict__ Sc)
{
    __shared__ float Qt[16][65];
    __shared__ float Ks[64 * 257];     // Ks[hd][sl], pad 257 -> conflict-free
    int tid = threadIdx.x;
    int t0 = blockIdx.x * 16;
    int bh = blockIdx.y;
    int bb = bh >> 3;
    int ty = tid >> 6, tx = tid & 63;  // ty = wave in [0,4), tx = lane

    for (int p = 0; p < 4; ++p) {
        int x = tid + p * 256;         // 16*64 = 1024
        Qt[x >> 6][x & 63] = Q[((size_t)bh * TT + t0 + (x >> 6)) * HDim + (x & 63)];
    }
    const float* Kp = K + (size_t)bh * SSZ * HDim;

    for (int s0 = 0; s0 < SSZ; s0 += 256) {
        for (int p = 0; p < 64; ++p) {
            int x = tid + p * 256;     // 256*64 = 16384
            int sl = x >> 6, c = x & 63;
            Ks[c * 257 + sl] = Kp[(size_t)(s0 + sl) * HDim + c];
        }
        __syncthreads();
        float acc[4][4];
        for (int i = 0; i < 4; ++i)
            for (int j = 0; j < 4; ++j) acc[i][j] = 0.f;
        for (int hd = 0; hd < 64; ++hd) {
            float a[4], b[4];
            for (int i = 0; i < 4; ++i) a[i] = Qt[ty * 4 + i][hd];        // broadcast
            for (int j = 0; j < 4; ++j) b[j] = Ks[hd * 257 + tx + 64 * j]; // consecutive
            for (int i = 0; i < 4; ++i)
                for (int j = 0; j < 4; ++j) acc[i][j] += a[i] * b[j];
        }
        __syncthreads();               // Ks reads done before next staging
        int okj[4];
        for (int j = 0; j < 4; ++j) okj[j] = kpm[bb * SSZ + s0 + tx + 64 * j];
        for (int i = 0; i < 4; ++i) {
            int t = t0 + ty * 4 + i;
            for (int j = 0; j < 4; ++j) {
                int s = s0 + tx + 64 * j;
                float v = acc[i][j] * 0.125f + amask[(size_t)t * SSZ + s];
                if (okj[j] == 0) v = -1e30f;
                Sc[((size_t)bh * TT + t) * SSZ + s] = v;
            }
        }
    }
}

// ---------------- in-place row softmax over S=2048, one block per row
__global__ __launch_bounds__(256) void softmax_inplace(float* __restrict__ Sc)
{
    __shared__ float red[8];
    size_t row = blockIdx.x;
    float* p = Sc + row * SSZ;
    int tid = threadIdx.x;
    f32x4 v0 = *(f32x4*)(p + tid * 8);
    f32x4 v1 = *(f32x4*)(p + tid * 8 + 4);
    float m = fmaxf(fmaxf(fmaxf(v0[0], v0[1]), fmaxf(v0[2], v0[3])),
                    fmaxf(fmaxf(v1[0], v1[1]), fmaxf(v1[2], v1[3])));
    for (int off = 32; off; off >>= 1) m = fmaxf(m, __shfl_xor(m, off));
    if ((tid & 63) == 0) red[tid >> 6] = m;
    __syncthreads();
    m = fmaxf(fmaxf(red[0], red[1]), fmaxf(red[2], red[3]));
    float e[8], l = 0.f;
    for (int k = 0; k < 4; ++k) { e[k] = __expf(v0[k] - m); l += e[k]; }
    for (int k = 0; k < 4; ++k) { e[4 + k] = __expf(v1[k] - m); l += e[4 + k]; }
    for (int off = 32; off; off >>= 1) l += __shfl_xor(l, off);
    if ((tid & 63) == 0) red[4 + (tid >> 6)] = l;   // disjoint slots, no hazard
    __syncthreads();
    l = red[4] + red[5] + red[6] + red[7];
    float inv = 1.0f / l;
    f32x4 w0 = { e[0] * inv, e[1] * inv, e[2] * inv, e[3] * inv };
    f32x4 w1 = { e[4] * inv, e[5] * inv, e[6] * inv, e[7] * inv };
    *(f32x4*)(p + tid * 8) = w0;
    *(f32x4*)(p + tid * 8 + 4) = w1;
}

// ---------------- PV: AO[b][t][h*64+hd] = sum_s W[bh][t][s] * V[bh][s][hd]
__global__ __launch_bounds__(256) void pv_f32(
    const float* __restrict__ Wt, const float* __restrict__ V,
    float* __restrict__ AO)
{
    __shared__ float Vs[128 * 65];
    __shared__ float Ws[16][132];
    int tid = threadIdx.x;
    int t0 = blockIdx.x * 16;
    int bh = blockIdx.y;
    int bb = bh >> 3, h = bh & 7;
    int ty = tid >> 5, tx = tid & 31;   // ty<8, tx<32

    const float* Vp = V + (size_t)bh * SSZ * HDim;
    const float* Wp = Wt + ((size_t)bh * TT + t0) * SSZ;

    float acc[2][2] = {{0.f, 0.f}, {0.f, 0.f}};
    for (int s0 = 0; s0 < SSZ; s0 += 128) {
        for (int p = 0; p < 32; ++p) {
            int x = tid + p * 256;      // 128*64 = 8192
            int sl = x >> 6, c = x & 63;
            Vs[sl * 65 + c] = Vp[(size_t)(s0 + sl) * HDim + c];
        }
        for (int p = 0; p < 8; ++p) {
            int x = tid + p * 256;      // 16*128 = 2048
            int r = x >> 7, c = x & 127;
            Ws[r][c] = Wp[(size_t)r * SSZ + s0 + c];
        }
        __syncthreads();
        for (int sl = 0; sl < 128; ++sl) {
            float a0 = Ws[ty * 2][sl], a1 = Ws[ty * 2 + 1][sl];
            float b0 = Vs[sl * 65 + tx * 2], b1 = Vs[sl * 65 + tx * 2 + 1];
            acc[0][0] += a0 * b0; acc[0][1] += a0 * b1;
            acc[1][0] += a1 * b0; acc[1][1] += a1 * b1;
        }
        __syncthreads();
    }
    for (int i = 0; i < 2; ++i)
        for (int j = 0; j < 2; ++j) {
            int t = t0 + ty * 2 + i, hd = tx * 2 + j;
            AO[((size_t)bb * TT + t) * DQq + h * HDim + hd] = acc[i][j];
        }
}

extern "C" void kernel_launch(void* const* d_in, const int* in_sizes, int n_in,
                              void* d_out, int out_size, void* d_ws, size_t ws_size,
                              hipStream_t stream)
{
    const float* query = (const float*)d_in[0];
    const float* key   = (const float*)d_in[1];
    const float* value = (const float*)d_in[2];
    const int*   kpm   = (const int*)d_in[3];
    const float* amask = (const float*)d_in[4];
    const float* Wq = (const float*)d_in[5];
    const float* bq = (const float*)d_in[6];
    const float* Wk = (const float*)d_in[7];
    const float* bk = (const float*)d_in[8];
    const float* Wv = (const float*)d_in[9];
    const float* bv = (const float*)d_in[10];
    const float* Wo = (const float*)d_in[11];
    const float* bo = (const float*)d_in[12];

    char* ws = (char*)d_ws;
    float* Qh = (float*)ws;  ws += (size_t)BB * NH * TT * HDim * 4;   // 16 MB
    float* Kh = (float*)ws;  ws += (size_t)BB * NH * SSZ * HDim * 4;  // 16 MB
    float* Vh = (float*)ws;  ws += (size_t)BB * NH * SSZ * HDim * 4;  // 16 MB
    float* AO = (float*)ws;  ws += (size_t)BB * TT * DQq * 4;         // 16 MB

    float* out0  = (float*)d_out;
    float* attnW = out0 + (size_t)BB * TT * DQq;   // output 1 region, also scratch

    dim3 gp(8192 / 64, 512 / 64);
    proj_f32<0><<<gp, 256, 0, stream>>>(query, Wq, bq, Qh, 512);
    proj_f32<0><<<gp, 256, 0, stream>>>(key,   Wk, bk, Kh, 1024);
    proj_f32<0><<<gp, 256, 0, stream>>>(value, Wv, bv, Vh, 1024);

    dim3 ga(TT / 16, BB * NH);
    scores_f32<<<ga, 256, 0, stream>>>(Qh, Kh, kpm, amask, attnW);
    softmax_inplace<<<BB * NH * TT, 256, 0, stream>>>(attnW);
    pv_f32<<<ga, 256, 0, stream>>>(attnW, Vh, AO);

    proj_f32<1><<<gp, 256, 0, stream>>>(AO, Wo, bo, out0, 512);
}

// Round 5
// 1715.890 us; speedup vs baseline: 1.0097x; 1.0097x over previous
//
#include <hip/hip_runtime.h>
#include <hip/hip_bf16.h>

#define BB 4
#define TT 2048
#define SSZ 2048
#define DQq 512
#define NH 8
#define HDim 64

typedef __attribute__((ext_vector_type(8))) short short8;
typedef __attribute__((ext_vector_type(4))) float f32x4;

__device__ __forceinline__ short f2bf(float f) {
    union { float f; unsigned u; } v; v.f = f;
    unsigned r = v.u + 0x7fffu + ((v.u >> 16) & 1u);
    return (short)(r >> 16);
}
__device__ __forceinline__ float bf2f(short s) {
    union { unsigned u; float f; } v; v.u = ((unsigned)(unsigned short)s) << 16;
    return v.f;
}

// ---------------- weight transpose + bf16 convert: W[Kd][512] -> Wt[512][Kd]
__global__ void wt_kernel(const float* __restrict__ W, short* __restrict__ Wt, int Kd) {
    int tid = blockIdx.x * 256 + threadIdx.x;
    int n = tid / Kd, k = tid - n * Kd;
    Wt[tid] = f2bf(W[(size_t)k * DQq + n]);
}

// ---------------- projection GEMM: X[M,Kd] @ W[Kd,512] + b   (MFMA bf16)
// MODE 0: out bf16 [B,H,L,64]; MODE 1: out bf16 [B,H,64,S] (V^T); MODE 2: f32 [M,512]
template<int MODE, bool IN_BF16>
__global__ __launch_bounds__(256) void gemm_proj(
    const void* __restrict__ Xv, const short* __restrict__ Wt,
    const float* __restrict__ bias, void* __restrict__ Out, int Kd)
{
    __shared__ short As[64 * 40];
    __shared__ short Bs[64 * 40];
    int tid = threadIdx.x;
    int wave = tid >> 6, lane = tid & 63;
    int g = lane >> 4, r = lane & 15;
    int wm = wave >> 1, wn = wave & 1;
    int m0 = blockIdx.x * 64, n0 = blockIdx.y * 64;

    const float* Xf = (const float*)Xv;
    const short* Xb = (const short*)Xv;

    f32x4 acc[2][2];
    for (int a = 0; a < 2; ++a) for (int b2 = 0; b2 < 2; ++b2) acc[a][b2] = (f32x4){0.f,0.f,0.f,0.f};

    int lrow = tid >> 2, lk = (tid & 3) * 8;

    for (int k0 = 0; k0 < Kd; k0 += 32) {
        short8 av;
        if (IN_BF16) {
            av = *(const short8*)(Xb + (size_t)(m0 + lrow) * Kd + k0 + lk);
        } else {
            const f32x4* p = (const f32x4*)(Xf + (size_t)(m0 + lrow) * Kd + k0 + lk);
            f32x4 x0 = p[0], x1 = p[1];
            av[0]=f2bf(x0[0]); av[1]=f2bf(x0[1]); av[2]=f2bf(x0[2]); av[3]=f2bf(x0[3]);
            av[4]=f2bf(x1[0]); av[5]=f2bf(x1[1]); av[6]=f2bf(x1[2]); av[7]=f2bf(x1[3]);
        }
        *(short8*)(As + lrow * 40 + lk) = av;
        short8 bv = *(const short8*)(Wt + (size_t)(n0 + lrow) * Kd + k0 + lk);
        *(short8*)(Bs + lrow * 40 + lk) = bv;
        __syncthreads();
        short8 af[2], bf[2];
        for (int mi = 0; mi < 2; ++mi)
            af[mi] = *(short8*)(As + (wm*32 + mi*16 + r) * 40 + g*8);
        for (int ni = 0; ni < 2; ++ni)
            bf[ni] = *(short8*)(Bs + (wn*32 + ni*16 + r) * 40 + g*8);
        for (int mi = 0; mi < 2; ++mi)
            for (int ni = 0; ni < 2; ++ni)
                acc[mi][ni] = __builtin_amdgcn_mfma_f32_16x16x32_bf16(af[mi], bf[ni], acc[mi][ni], 0, 0, 0);
        __syncthreads();
    }

    for (int mi = 0; mi < 2; ++mi)
      for (int ni = 0; ni < 2; ++ni)
        for (int i = 0; i < 4; ++i) {
            int m = m0 + wm*32 + mi*16 + g*4 + i;
            int n = n0 + wn*32 + ni*16 + r;
            float v = acc[mi][ni][i] + bias[n];
            if (MODE == 0) {
                int b = m >> 11, t = m & 2047, h = n >> 6, hd = n & 63;
                ((short*)Out)[((((size_t)b*NH + h)*TT + t) << 6) + hd] = f2bf(v);
            } else if (MODE == 1) {
                int b = m >> 11, t = m & 2047, h = n >> 6, hd = n & 63;
                ((short*)Out)[(((size_t)b*NH + h)*HDim + hd)*SSZ + t] = f2bf(v);
            } else {
                ((float*)Out)[(size_t)m * DQq + n] = v;
            }
        }
}

// ---------------- scores from bf16 Q,K [B,H,L,64]  (round-3-proven structure)
__global__ __launch_bounds__(256) void scores_bf16(
    const short* __restrict__ Q, const short* __restrict__ K,
    const int* __restrict__ kpm, const float* __restrict__ amask,
    float* __restrict__ Sc)
{
    __shared__ float Qt[16][65];
    __shared__ float Ks[64 * 257];
    int tid = threadIdx.x;
    int t0 = blockIdx.x * 16;
    int bh = blockIdx.y;
    int bb = bh >> 3;
    int ty = tid >> 6, tx = tid & 63;

    for (int p = 0; p < 4; ++p) {
        int x = tid + p * 256;
        Qt[x >> 6][x & 63] = bf2f(Q[((size_t)bh * TT + t0 + (x >> 6)) * HDim + (x & 63)]);
    }
    const short* Kp = K + (size_t)bh * SSZ * HDim;

    for (int s0 = 0; s0 < SSZ; s0 += 256) {
        for (int p = 0; p < 64; ++p) {
            int x = tid + p * 256;
            int sl = x >> 6, c = x & 63;
            Ks[c * 257 + sl] = bf2f(Kp[(size_t)(s0 + sl) * HDim + c]);
        }
        __syncthreads();
        float acc[4][4];
        for (int i = 0; i < 4; ++i)
            for (int j = 0; j < 4; ++j) acc[i][j] = 0.f;
        for (int hd = 0; hd < 64; ++hd) {
            float a[4], b[4];
            for (int i = 0; i < 4; ++i) a[i] = Qt[ty * 4 + i][hd];
            for (int j = 0; j < 4; ++j) b[j] = Ks[hd * 257 + tx + 64 * j];
            for (int i = 0; i < 4; ++i)
                for (int j = 0; j < 4; ++j) acc[i][j] += a[i] * b[j];
        }
        __syncthreads();
        int okj[4];
        for (int j = 0; j < 4; ++j) okj[j] = kpm[bb * SSZ + s0 + tx + 64 * j];
        for (int i = 0; i < 4; ++i) {
            int t = t0 + ty * 4 + i;
            for (int j = 0; j < 4; ++j) {
                int s = s0 + tx + 64 * j;
                float v = acc[i][j] * 0.125f + amask[(size_t)t * SSZ + s];
                if (okj[j] == 0) v = -1e30f;
                Sc[((size_t)bh * TT + t) * SSZ + s] = v;
            }
        }
    }
}

// ---------------- in-place row softmax (round-3-proven, unchanged)
__global__ __launch_bounds__(256) void softmax_inplace(float* __restrict__ Sc)
{
    __shared__ float red[8];
    size_t row = blockIdx.x;
    float* p = Sc + row * SSZ;
    int tid = threadIdx.x;
    f32x4 v0 = *(f32x4*)(p + tid * 8);
    f32x4 v1 = *(f32x4*)(p + tid * 8 + 4);
    float m = fmaxf(fmaxf(fmaxf(v0[0], v0[1]), fmaxf(v0[2], v0[3])),
                    fmaxf(fmaxf(v1[0], v1[1]), fmaxf(v1[2], v1[3])));
    for (int off = 32; off; off >>= 1) m = fmaxf(m, __shfl_xor(m, off));
    if ((tid & 63) == 0) red[tid >> 6] = m;
    __syncthreads();
    m = fmaxf(fmaxf(red[0], red[1]), fmaxf(red[2], red[3]));
    float e[8], l = 0.f;
    for (int k = 0; k < 4; ++k) { e[k] = __expf(v0[k] - m); l += e[k]; }
    for (int k = 0; k < 4; ++k) { e[4 + k] = __expf(v1[k] - m); l += e[4 + k]; }
    for (int off = 32; off; off >>= 1) l += __shfl_xor(l, off);
    if ((tid & 63) == 0) red[4 + (tid >> 6)] = l;
    __syncthreads();
    l = red[4] + red[5] + red[6] + red[7];
    float inv = 1.0f / l;
    f32x4 w0 = { e[0] * inv, e[1] * inv, e[2] * inv, e[3] * inv };
    f32x4 w1 = { e[4] * inv, e[5] * inv, e[6] * inv, e[7] * inv };
    *(f32x4*)(p + tid * 8) = w0;
    *(f32x4*)(p + tid * 8 + 4) = w1;
}

// ---------------- PV from bf16 V^T [B,H,64,S]; AO f32 [M,512]
__global__ __launch_bounds__(256) void pv_bf16T(
    const float* __restrict__ Wt, const short* __restrict__ Vt,
    float* __restrict__ AO)
{
    __shared__ float Vs[128 * 65];
    __shared__ float Ws[16][132];
    int tid = threadIdx.x;
    int t0 = blockIdx.x * 16;
    int bh = blockIdx.y;
    int bb = bh >> 3, h = bh & 7;
    int ty = tid >> 5, tx = tid & 31;

    const short* Vp = Vt + (size_t)bh * HDim * SSZ;
    const float* Wp = Wt + ((size_t)bh * TT + t0) * SSZ;

    float acc[2][2] = {{0.f, 0.f}, {0.f, 0.f}};
    for (int s0 = 0; s0 < SSZ; s0 += 128) {
        for (int p = 0; p < 32; ++p) {
            int x = tid + p * 256;      // 64 hd x 128 sl
            int hd = x >> 7, sl = x & 127;
            Vs[sl * 65 + hd] = bf2f(Vp[(size_t)hd * SSZ + s0 + sl]);
        }
        for (int p = 0; p < 8; ++p) {
            int x = tid + p * 256;      // 16*128
            int rr = x >> 7, c = x & 127;
            Ws[rr][c] = Wp[(size_t)rr * SSZ + s0 + c];
        }
        __syncthreads();
        for (int sl = 0; sl < 128; ++sl) {
            float a0 = Ws[ty * 2][sl], a1 = Ws[ty * 2 + 1][sl];
            float b0 = Vs[sl * 65 + tx * 2], b1 = Vs[sl * 65 + tx * 2 + 1];
            acc[0][0] += a0 * b0; acc[0][1] += a0 * b1;
            acc[1][0] += a1 * b0; acc[1][1] += a1 * b1;
        }
        __syncthreads();
    }
    for (int i = 0; i < 2; ++i)
        for (int j = 0; j < 2; ++j) {
            int t = t0 + ty * 2 + i, hd = tx * 2 + j;
            AO[((size_t)bb * TT + t) * DQq + h * HDim + hd] = acc[i][j];
        }
}

// ---------------- fused attention (round-4 code, byte-identical; under test)
__global__ __launch_bounds__(256) void attn_fused(
    const short* __restrict__ Q, const short* __restrict__ K, const short* __restrict__ Vt,
    const int* __restrict__ kpm, const float* __restrict__ amask,
    float* __restrict__ attnW, short* __restrict__ AO)
{
    __shared__ float s_wm[4][16];
    __shared__ float s_wl[4][16];
    __shared__ float s_m[16];
    __shared__ float s_li[16];
    __shared__ __align__(16) short wT[2][4][16][40];
    __shared__ float sOut[4][16][64];

    int tid = threadIdx.x;
    int wave = tid >> 6, lane = tid & 63;
    int g = lane >> 4, r = lane & 15;
    int t0 = blockIdx.x * 16;
    int bh = blockIdx.y;
    int b = bh >> 3;

    const short* Qp = Q + ((size_t)bh * TT + t0) * HDim;
    const short* Kp = K + (size_t)bh * SSZ * HDim;
    const short* Vp = Vt + (size_t)bh * HDim * SSZ;

    short8 qf0 = *(const short8*)(Qp + r * HDim + g * 8);
    short8 qf1 = *(const short8*)(Qp + r * HDim + 32 + g * 8);

    int ws0 = wave * 512;
    float mrun[4], lrun[4];
    for (int i = 0; i < 4; ++i) { mrun[i] = -1e30f; lrun[i] = 0.f; }

    for (int c = 0; c < 32; ++c) {
        int s_idx = ws0 + c * 16 + r;
        short8 kf0 = *(const short8*)(Kp + (size_t)s_idx * HDim + g * 8);
        short8 kf1 = *(const short8*)(Kp + (size_t)s_idx * HDim + 32 + g * 8);
        f32x4 sc = (f32x4){0.f,0.f,0.f,0.f};
        sc = __builtin_amdgcn_mfma_f32_16x16x32_bf16(qf0, kf0, sc, 0, 0, 0);
        sc = __builtin_amdgcn_mfma_f32_16x16x32_bf16(qf1, kf1, sc, 0, 0, 0);
        int ok = kpm[b * SSZ + s_idx];
        for (int i = 0; i < 4; ++i) {
            float v = sc[i] * 0.125f + amask[(size_t)(t0 + g*4 + i) * SSZ + s_idx];
            if (!ok) v = -1e30f;
            float mn = fmaxf(mrun[i], v);
            lrun[i] = lrun[i] * __expf(mrun[i] - mn) + __expf(v - mn);
            mrun[i] = mn;
        }
    }
    for (int i = 0; i < 4; ++i) {
        for (int off = 1; off < 16; off <<= 1) {
            float mo = __shfl_xor(mrun[i], off);
            float lo = __shfl_xor(lrun[i], off);
            float mn = fmaxf(mrun[i], mo);
            lrun[i] = lrun[i] * __expf(mrun[i] - mn) + lo * __expf(mo - mn);
            mrun[i] = mn;
        }
    }
    if (r == 0)
        for (int i = 0; i < 4; ++i) {
            s_wm[wave][g * 4 + i] = mrun[i];
            s_wl[wave][g * 4 + i] = lrun[i];
        }
    __syncthreads();
    if (tid < 16) {
        float m = -1e30f;
        for (int w = 0; w < 4; ++w) m = fmaxf(m, s_wm[w][tid]);
        float l = 0.f;
        for (int w = 0; w < 4; ++w) l += s_wl[w][tid] * __expf(s_wm[w][tid] - m);
        s_m[tid] = m;
        s_li[tid] = 1.0f / l;
    }
    __syncthreads();

    float mr[4], lr[4];
    for (int i = 0; i < 4; ++i) { mr[i] = s_m[g*4 + i]; lr[i] = s_li[g*4 + i]; }

    f32x4 oacc[4];
    for (int i = 0; i < 4; ++i) oacc[i] = (f32x4){0.f,0.f,0.f,0.f};

    for (int c2 = 0; c2 < 16; ++c2) {
        int col0 = ws0 + c2 * 32;
        short* wtile = &wT[c2 & 1][wave][0][0];
        for (int h2 = 0; h2 < 2; ++h2) {
            int s_idx = col0 + h2 * 16 + r;
            short8 kf0 = *(const short8*)(Kp + (size_t)s_idx * HDim + g * 8);
            short8 kf1 = *(const short8*)(Kp + (size_t)s_idx * HDim + 32 + g * 8);
            f32x4 sc = (f32x4){0.f,0.f,0.f,0.f};
            sc = __builtin_amdgcn_mfma_f32_16x16x32_bf16(qf0, kf0, sc, 0, 0, 0);
            sc = __builtin_amdgcn_mfma_f32_16x16x32_bf16(qf1, kf1, sc, 0, 0, 0);
            int ok = kpm[b * SSZ + s_idx];
            for (int i = 0; i < 4; ++i) {
                float v = sc[i] * 0.125f + amask[(size_t)(t0 + g*4 + i) * SSZ + s_idx];
                if (!ok) v = -1e30f;
                float w = __expf(v - mr[i]) * lr[i];
                attnW[((size_t)bh * TT + t0 + g*4 + i) * SSZ + s_idx] = w;
                wtile[(g*4 + i) * 40 + h2 * 16 + r] = f2bf(w);
            }
        }
        __syncthreads();
        short8 wf = *(short8*)(wtile + r * 40 + g * 8);
        for (int n4 = 0; n4 < 4; ++n4) {
            short8 vf = *(const short8*)(Vp + (size_t)(n4 * 16 + r) * SSZ + col0 + g * 8);
            oacc[n4] = __builtin_amdgcn_mfma_f32_16x16x32_bf16(wf, vf, oacc[n4], 0, 0, 0);
        }
    }

    __syncthreads();
    for (int n4 = 0; n4 < 4; ++n4)
        for (int i = 0; i < 4; ++i)
            sOut[wave][g * 4 + i][n4 * 16 + r] = oacc[n4][i];
    __syncthreads();
    int h = bh & 7;
    for (int u = 0; u < 4; ++u) {
        int pos = tid + u * 256;
        int t = pos >> 6, hd = pos & 63;
        float sum = sOut[0][t][hd] + sOut[1][t][hd] + sOut[2][t][hd] + sOut[3][t][hd];
        AO[((size_t)(b * TT + t0 + t)) * DQq + h * HDim + hd] = f2bf(sum);
    }
}

extern "C" void kernel_launch(void* const* d_in, const int* in_sizes, int n_in,
                              void* d_out, int out_size, void* d_ws, size_t ws_size,
                              hipStream_t stream)
{
    const float* query = (const float*)d_in[0];
    const float* key   = (const float*)d_in[1];
    const float* value = (const float*)d_in[2];
    const int*   kpm   = (const int*)d_in[3];
    const float* amask = (const float*)d_in[4];
    const float* Wq = (const float*)d_in[5];
    const float* bq = (const float*)d_in[6];
    const float* Wk = (const float*)d_in[7];
    const float* bk = (const float*)d_in[8];
    const float* Wv = (const float*)d_in[9];
    const float* bv = (const float*)d_in[10];
    const float* Wo = (const float*)d_in[11];
    const float* bo = (const float*)d_in[12];

    char* ws = (char*)d_ws;
    short* WqT = (short*)ws;  ws += (size_t)512 * 512 * 2;
    short* WkT = (short*)ws;  ws += (size_t)512 * 1024 * 2;
    short* WvT = (short*)ws;  ws += (size_t)512 * 1024 * 2;
    short* WoT = (short*)ws;  ws += (size_t)512 * 512 * 2;
    short* Qh  = (short*)ws;  ws += (size_t)BB * NH * TT * HDim * 2;
    short* Kh  = (short*)ws;  ws += (size_t)BB * NH * SSZ * HDim * 2;
    short* Vth = (short*)ws;  ws += (size_t)BB * NH * HDim * SSZ * 2;
    float* AOf = (float*)ws;  ws += (size_t)BB * TT * DQq * 4;
    short* AO2 = (short*)AOf;   // reused after O-projection consumed AOf

    float* out0  = (float*)d_out;
    float* attnW = out0 + (size_t)BB * TT * DQq;

    wt_kernel<<<(512*512)/256, 256, 0, stream>>>(Wq, WqT, 512);
    wt_kernel<<<(1024*512)/256, 256, 0, stream>>>(Wk, WkT, 1024);
    wt_kernel<<<(1024*512)/256, 256, 0, stream>>>(Wv, WvT, 1024);
    wt_kernel<<<(512*512)/256, 256, 0, stream>>>(Wo, WoT, 512);

    dim3 gp(8192 / 64, 512 / 64);
    gemm_proj<0, false><<<gp, 256, 0, stream>>>(query, WqT, bq, Qh, 512);
    gemm_proj<0, false><<<gp, 256, 0, stream>>>(key,   WkT, bk, Kh, 1024);
    gemm_proj<1, false><<<gp, 256, 0, stream>>>(value, WvT, bv, Vth, 1024);

    dim3 ga(TT / 16, BB * NH);
    // ---- output-0 path: proven f32 attention core on bf16 projections
    scores_bf16<<<ga, 256, 0, stream>>>(Qh, Kh, kpm, amask, attnW);
    softmax_inplace<<<BB * NH * TT, 256, 0, stream>>>(attnW);
    pv_bf16T<<<ga, 256, 0, stream>>>(attnW, Vth, AOf);
    gemm_proj<2, false><<<gp, 256, 0, stream>>>(AOf, WoT, bo, out0, 512);

    // ---- output-1 path: MFMA attn under test (overwrites attnW region last)
    attn_fused<<<ga, 256, 0, stream>>>(Qh, Kh, Vth, kpm, amask, attnW, AO2);
}

// Round 8
// 754.393 us; speedup vs baseline: 2.2967x; 2.2745x over previous
//
#include <hip/hip_runtime.h>
#include <hip/hip_bf16.h>

#define BB 4
#define TT 2048
#define SSZ 2048
#define DQq 512
#define NH 8
#define HDim 64

typedef __attribute__((ext_vector_type(8))) short short8;
typedef __attribute__((ext_vector_type(4))) float f32x4;

__device__ __forceinline__ short f2bf(float f) {
    union { float f; unsigned u; } v; v.f = f;
    unsigned r = v.u + 0x7fffu + ((v.u >> 16) & 1u);
    return (short)(r >> 16);
}

// ---------------- weight transpose + bf16 convert: W[Kd][512] -> Wt[512][Kd]
// (verified round 5)
__global__ void wt_kernel(const float* __restrict__ W, short* __restrict__ Wt, int Kd) {
    int tid = blockIdx.x * 256 + threadIdx.x;
    int n = tid / Kd, k = tid - n * Kd;
    Wt[tid] = f2bf(W[(size_t)k * DQq + n]);
}

// ---------------- projection GEMM (verified round 5, unchanged)
template<int MODE, bool IN_BF16>
__global__ __launch_bounds__(256) void gemm_proj(
    const void* __restrict__ Xv, const short* __restrict__ Wt,
    const float* __restrict__ bias, void* __restrict__ Out, int Kd)
{
    __shared__ short As[64 * 40];
    __shared__ short Bs[64 * 40];
    int tid = threadIdx.x;
    int wave = tid >> 6, lane = tid & 63;
    int g = lane >> 4, r = lane & 15;
    int wm = wave >> 1, wn = wave & 1;
    int m0 = blockIdx.x * 64, n0 = blockIdx.y * 64;

    const float* Xf = (const float*)Xv;
    const short* Xb = (const short*)Xv;

    f32x4 acc[2][2];
    for (int a = 0; a < 2; ++a) for (int b2 = 0; b2 < 2; ++b2) acc[a][b2] = (f32x4){0.f,0.f,0.f,0.f};

    int lrow = tid >> 2, lk = (tid & 3) * 8;

    for (int k0 = 0; k0 < Kd; k0 += 32) {
        short8 av;
        if (IN_BF16) {
            av = *(const short8*)(Xb + (size_t)(m0 + lrow) * Kd + k0 + lk);
        } else {
            const f32x4* p = (const f32x4*)(Xf + (size_t)(m0 + lrow) * Kd + k0 + lk);
            f32x4 x0 = p[0], x1 = p[1];
            av[0]=f2bf(x0[0]); av[1]=f2bf(x0[1]); av[2]=f2bf(x0[2]); av[3]=f2bf(x0[3]);
            av[4]=f2bf(x1[0]); av[5]=f2bf(x1[1]); av[6]=f2bf(x1[2]); av[7]=f2bf(x1[3]);
        }
        *(short8*)(As + lrow * 40 + lk) = av;
        short8 bv = *(const short8*)(Wt + (size_t)(n0 + lrow) * Kd + k0 + lk);
        *(short8*)(Bs + lrow * 40 + lk) = bv;
        __syncthreads();
        short8 af[2], bf[2];
        for (int mi = 0; mi < 2; ++mi)
            af[mi] = *(short8*)(As + (wm*32 + mi*16 + r) * 40 + g*8);
        for (int ni = 0; ni < 2; ++ni)
            bf[ni] = *(short8*)(Bs + (wn*32 + ni*16 + r) * 40 + g*8);
        for (int mi = 0; mi < 2; ++mi)
            for (int ni = 0; ni < 2; ++ni)
                acc[mi][ni] = __builtin_amdgcn_mfma_f32_16x16x32_bf16(af[mi], bf[ni], acc[mi][ni], 0, 0, 0);
        __syncthreads();
    }

    for (int mi = 0; mi < 2; ++mi)
      for (int ni = 0; ni < 2; ++ni)
        for (int i = 0; i < 4; ++i) {
            int m = m0 + wm*32 + mi*16 + g*4 + i;
            int n = n0 + wn*32 + ni*16 + r;
            float v = acc[mi][ni][i] + bias[n];
            if (MODE == 0) {
                int b = m >> 11, t = m & 2047, h = n >> 6, hd = n & 63;
                ((short*)Out)[((((size_t)b*NH + h)*TT + t) << 6) + hd] = f2bf(v);
            } else if (MODE == 1) {
                int b = m >> 11, t = m & 2047, h = n >> 6, hd = n & 63;
                ((short*)Out)[(((size_t)b*NH + h)*HDim + hd)*SSZ + t] = f2bf(v);
            } else {
                ((float*)Out)[(size_t)m * DQq + n] = v;
            }
        }
}

// ---------------- attention weights only (verified round 5 dataflow:
// phase-1 stats + phase-2 recompute + scalar attnW writes; PV code deleted)
__global__ __launch_bounds__(256) void attn_w(
    const short* __restrict__ Q, const short* __restrict__ K,
    const int* __restrict__ kpm, const float* __restrict__ amask,
    float* __restrict__ attnW)
{
    __shared__ float s_wm[4][16];
    __shared__ float s_wl[4][16];
    __shared__ float s_m[16];
    __shared__ float s_li[16];

    int tid = threadIdx.x;
    int wave = tid >> 6, lane = tid & 63;
    int g = lane >> 4, r = lane & 15;
    int t0 = blockIdx.x * 16;
    int bh = blockIdx.y;
    int b = bh >> 3;

    const short* Qp = Q + ((size_t)bh * TT + t0) * HDim;
    const short* Kp = K + (size_t)bh * SSZ * HDim;

    short8 qf0 = *(const short8*)(Qp + r * HDim + g * 8);
    short8 qf1 = *(const short8*)(Qp + r * HDim + 32 + g * 8);

    int ws0 = wave * 512;
    float mrun[4], lrun[4];
    for (int i = 0; i < 4; ++i) { mrun[i] = -1e30f; lrun[i] = 0.f; }

    // ---- phase 1: online stats (verified)
    for (int c = 0; c < 32; ++c) {
        int s_idx = ws0 + c * 16 + r;
        short8 kf0 = *(const short8*)(Kp + (size_t)s_idx * HDim + g * 8);
        short8 kf1 = *(const short8*)(Kp + (size_t)s_idx * HDim + 32 + g * 8);
        f32x4 sc = (f32x4){0.f,0.f,0.f,0.f};
        sc = __builtin_amdgcn_mfma_f32_16x16x32_bf16(qf0, kf0, sc, 0, 0, 0);
        sc = __builtin_amdgcn_mfma_f32_16x16x32_bf16(qf1, kf1, sc, 0, 0, 0);
        int ok = kpm[b * SSZ + s_idx];
        for (int i = 0; i < 4; ++i) {
            float v = sc[i] * 0.125f + amask[(size_t)(t0 + g*4 + i) * SSZ + s_idx];
            if (!ok) v = -1e30f;
            float mn = fmaxf(mrun[i], v);
            lrun[i] = lrun[i] * __expf(mrun[i] - mn) + __expf(v - mn);
            mrun[i] = mn;
        }
    }
    for (int i = 0; i < 4; ++i) {
        for (int off = 1; off < 16; off <<= 1) {
            float mo = __shfl_xor(mrun[i], off);
            float lo = __shfl_xor(lrun[i], off);
            float mn = fmaxf(mrun[i], mo);
            lrun[i] = lrun[i] * __expf(mrun[i] - mn) + lo * __expf(mo - mn);
            mrun[i] = mn;
        }
    }
    if (r == 0)
        for (int i = 0; i < 4; ++i) {
            s_wm[wave][g * 4 + i] = mrun[i];
            s_wl[wave][g * 4 + i] = lrun[i];
        }
    __syncthreads();
    if (tid < 16) {
        float m = -1e30f;
        for (int w = 0; w < 4; ++w) m = fmaxf(m, s_wm[w][tid]);
        float l = 0.f;
        for (int w = 0; w < 4; ++w) l += s_wl[w][tid] * __expf(s_wm[w][tid] - m);
        s_m[tid] = m;
        s_li[tid] = 1.0f / l;
    }
    __syncthreads();

    // ---- phase 2: recompute, normalize, write weights (verified pattern)
    float mr[4], lr[4];
    for (int i = 0; i < 4; ++i) { mr[i] = s_m[g*4 + i]; lr[i] = s_li[g*4 + i]; }

    for (int c2 = 0; c2 < 32; ++c2) {
        int s_idx = ws0 + c2 * 16 + r;
        short8 kf0 = *(const short8*)(Kp + (size_t)s_idx * HDim + g * 8);
        short8 kf1 = *(const short8*)(Kp + (size_t)s_idx * HDim + 32 + g * 8);
        f32x4 sc = (f32x4){0.f,0.f,0.f,0.f};
        sc = __builtin_amdgcn_mfma_f32_16x16x32_bf16(qf0, kf0, sc, 0, 0, 0);
        sc = __builtin_amdgcn_mfma_f32_16x16x32_bf16(qf1, kf1, sc, 0, 0, 0);
        int ok = kpm[b * SSZ + s_idx];
        for (int i = 0; i < 4; ++i) {
            float v = sc[i] * 0.125f + amask[(size_t)(t0 + g*4 + i) * SSZ + s_idx];
            if (!ok) v = -1e30f;
            float w = __expf(v - mr[i]) * lr[i];
            attnW[((size_t)bh * TT + t0 + g*4 + i) * SSZ + s_idx] = w;
        }
    }
}

// ---------------- PV via MFMA, separate kernel, no cross-lane plumbing.
// A-fragment gathered per-lane from global attnW (lane (g,r): w[t=r][8g+j]);
// B-fragment = V^T rows (pattern verified in phase 1); each wave owns one
// 16-wide hd tile -> no cross-wave reduction, direct f32 stores.
__global__ __launch_bounds__(256) void pv_mfma(
    const float* __restrict__ attnW, const short* __restrict__ Vt,
    float* __restrict__ AO)
{
    int tid = threadIdx.x;
    int wave = tid >> 6, lane = tid & 63;
    int g = lane >> 4, r = lane & 15;
    int t0 = blockIdx.x * 16;
    int bh = blockIdx.y;
    int b = bh >> 3, h = bh & 7;

    const float* wrow = attnW + ((size_t)bh * TT + t0 + r) * SSZ;
    const short* vrow = Vt + ((size_t)bh * HDim + wave * 16 + r) * SSZ;

    f32x4 oacc = (f32x4){0.f, 0.f, 0.f, 0.f};
    for (int c = 0; c < 64; ++c) {
        int col0 = c * 32 + g * 8;
        f32x4 w0 = *(const f32x4*)(wrow + col0);
        f32x4 w1 = *(const f32x4*)(wrow + col0 + 4);
        short8 wf;
        wf[0]=f2bf(w0[0]); wf[1]=f2bf(w0[1]); wf[2]=f2bf(w0[2]); wf[3]=f2bf(w0[3]);
        wf[4]=f2bf(w1[0]); wf[5]=f2bf(w1[1]); wf[6]=f2bf(w1[2]); wf[7]=f2bf(w1[3]);
        short8 vf = *(const short8*)(vrow + col0);
        oacc = __builtin_amdgcn_mfma_f32_16x16x32_bf16(wf, vf, oacc, 0, 0, 0);
    }
    // C/D: oacc[i] = PV[t = g*4+i][hd-local = r]; hd = wave*16 + r
    for (int i = 0; i < 4; ++i)
        AO[((size_t)(b * TT + t0 + g*4 + i)) * DQq + h * HDim + wave * 16 + r] = oacc[i];
}

extern "C" void kernel_launch(void* const* d_in, const int* in_sizes, int n_in,
                              void* d_out, int out_size, void* d_ws, size_t ws_size,
                              hipStream_t stream)
{
    const float* query = (const float*)d_in[0];
    const float* key   = (const float*)d_in[1];
    const float* value = (const float*)d_in[2];
    const int*   kpm   = (const int*)d_in[3];
    const float* amask = (const float*)d_in[4];
    const float* Wq = (const float*)d_in[5];
    const float* bq = (const float*)d_in[6];
    const float* Wk = (const float*)d_in[7];
    const float* bk = (const float*)d_in[8];
    const float* Wv = (const float*)d_in[9];
    const float* bv = (const float*)d_in[10];
    const float* Wo = (const float*)d_in[11];
    const float* bo = (const float*)d_in[12];

    char* ws = (char*)d_ws;
    short* WqT = (short*)ws;  ws += (size_t)512 * 512 * 2;
    short* WkT = (short*)ws;  ws += (size_t)512 * 1024 * 2;
    short* WvT = (short*)ws;  ws += (size_t)512 * 1024 * 2;
    short* WoT = (short*)ws;  ws += (size_t)512 * 512 * 2;
    short* Qh  = (short*)ws;  ws += (size_t)BB * NH * TT * HDim * 2;
    short* Kh  = (short*)ws;  ws += (size_t)BB * NH * SSZ * HDim * 2;
    short* Vth = (short*)ws;  ws += (size_t)BB * NH * HDim * SSZ * 2;
    float* AOf = (float*)ws;  ws += (size_t)BB * TT * DQq * 4;

    float* out0  = (float*)d_out;
    float* attnW = out0 + (size_t)BB * TT * DQq;

    wt_kernel<<<(512*512)/256, 256, 0, stream>>>(Wq, WqT, 512);
    wt_kernel<<<(1024*512)/256, 256, 0, stream>>>(Wk, WkT, 1024);
    wt_kernel<<<(1024*512)/256, 256, 0, stream>>>(Wv, WvT, 1024);
    wt_kernel<<<(512*512)/256, 256, 0, stream>>>(Wo, WoT, 512);

    dim3 gp(8192 / 64, 512 / 64);
    gemm_proj<0, false><<<gp, 256, 0, stream>>>(query, WqT, bq, Qh, 512);
    gemm_proj<0, false><<<gp, 256, 0, stream>>>(key,   WkT, bk, Kh, 1024);
    gemm_proj<1, false><<<gp, 256, 0, stream>>>(value, WvT, bv, Vth, 1024);

    dim3 ga(TT / 16, BB * NH);
    attn_w<<<ga, 256, 0, stream>>>(Qh, Kh, kpm, amask, attnW);
    pv_mfma<<<ga, 256, 0, stream>>>(attnW, Vth, AOf);

    gemm_proj<2, false><<<gp, 256, 0, stream>>>(AOf, WoT, bo, out0, 512);
}